// Round 7
// baseline (438.792 us; speedup 1.0000x reference)
//
#include <hip/hip_runtime.h>

// Op: out = (1/num_op) * sum_i ws[i] * SpMM(A_i, x).
// Pipeline: x->bf16 | coarse bucket count (row>>5, 1563 bins) | 1563 scan |
//           bucketed scatter (block-local runs, LDS rank) |
//           ballot-filter gather: ONE block per bucket, 16 waves x 2 rows.
// N=50000, D=128, NUM_OP=8, E=400000.

#define D_DIM 128
#define RPB_SHIFT 5
#define RPB 32
#define MAXB 2048
#define CHUNK 16384
#define SCAN_BLOCK 1024

static __device__ __forceinline__ unsigned short f2bf(float f) {
    unsigned int u = __float_as_uint(f);
    u += 0x7FFFu + ((u >> 16) & 1u);          // round-to-nearest-even
    return (unsigned short)(u >> 16);
}

static __device__ __forceinline__ unsigned long long pack2f(float a, float b) {
    return (unsigned long long)__float_as_uint(a)
         | ((unsigned long long)__float_as_uint(b) << 32);
}

// ---------- fallback (round-0) atomic scatter kernel ----------
__global__ __launch_bounds__(256) void spmm_scatter_kernel(
    const float* __restrict__ x, const float* __restrict__ edge_vals,
    const float* __restrict__ ws, const int* __restrict__ edge_rows,
    const int* __restrict__ edge_cols, float* __restrict__ out,
    int E, float inv_num)
{
    const int  op   = blockIdx.y;
    const long base = (long)op * (long)E;
    const float wscale = ws[op] * inv_num;
    const int lane = threadIdx.x & 63;
    const int wave = blockIdx.x * (blockDim.x >> 6) + (threadIdx.x >> 6);
    const int nwaves = gridDim.x * (blockDim.x >> 6);
    for (int e = wave; e < E; e += nwaves) {
        const int row = edge_rows[base + e];
        const int col = edge_cols[base + e];
        const float v = edge_vals[base + e] * wscale;
        const float2 xv = *reinterpret_cast<const float2*>(x + (long)col * D_DIM + lane * 2);
        float* o = out + (long)row * D_DIM + lane * 2;
        atomicAdd(o, xv.x * v);
        atomicAdd(o + 1, xv.y * v);
    }
}

// ---------- 0. x (f32) -> bf16 ----------
__global__ __launch_bounds__(256) void convert_kernel(
    const float4* __restrict__ x4, unsigned long long* __restrict__ xh, int n4)
{
    const int stride = gridDim.x * blockDim.x;
    for (int i = blockIdx.x * blockDim.x + threadIdx.x; i < n4; i += stride) {
        const float4 v = x4[i];
        const unsigned long long p =
            (unsigned long long)f2bf(v.x)
            | ((unsigned long long)f2bf(v.y) << 16)
            | ((unsigned long long)f2bf(v.z) << 32)
            | ((unsigned long long)f2bf(v.w) << 48);
        xh[i] = p;
    }
}

// ---------- 1. coarse bucket count (LDS-aggregated) ----------
__global__ __launch_bounds__(256) void bucket_count_kernel(
    const int* __restrict__ rows, int* __restrict__ gcount, long n, int B)
{
    __shared__ int h[MAXB];
    for (int i = threadIdx.x; i < B; i += 256) h[i] = 0;
    __syncthreads();
    for (long e = (long)blockIdx.x * 256 + threadIdx.x; e < n;
         e += (long)gridDim.x * 256)
        atomicAdd(&h[__builtin_nontemporal_load(&rows[e]) >> RPB_SHIFT], 1);
    __syncthreads();
    for (int i = threadIdx.x; i < B; i += 256)
        if (h[i]) atomicAdd(&gcount[i], h[i]);
}

// ---------- 2. exclusive scan (single block, proven multi-tile) ----------
__global__ __launch_bounds__(SCAN_BLOCK) void scan_kernel(
    int* __restrict__ cursors, int* __restrict__ offsets, int N)
{
    __shared__ int sdata[SCAN_BLOCK];
    __shared__ int carry_s;
    if (threadIdx.x == 0) carry_s = 0;
    __syncthreads();
    for (int base = 0; base < N; base += SCAN_BLOCK) {
        const int i = base + (int)threadIdx.x;
        const int v = (i < N) ? cursors[i] : 0;
        sdata[threadIdx.x] = v;
        __syncthreads();
        for (int ofs = 1; ofs < SCAN_BLOCK; ofs <<= 1) {
            int t = (threadIdx.x >= (unsigned)ofs) ? sdata[threadIdx.x - ofs] : 0;
            __syncthreads();
            sdata[threadIdx.x] += t;
            __syncthreads();
        }
        const int incl  = sdata[threadIdx.x];
        const int carry = carry_s;
        if (i < N) {
            const int excl = carry + incl - v;
            offsets[i] = excl;
            cursors[i] = excl;
        }
        __syncthreads();
        if (threadIdx.x == SCAN_BLOCK - 1) carry_s = carry + incl;
        __syncthreads();
    }
    if (threadIdx.x == 0) offsets[N] = carry_s;
}

// ---------- 3. bucketed scatter: per-block reservation + LDS rank ----------
__global__ __launch_bounds__(256) void scatter_bucket_kernel(
    const int* __restrict__ edge_rows, const int* __restrict__ edge_cols,
    const float* __restrict__ edge_vals, const float* __restrict__ ws,
    int* __restrict__ gcursor, unsigned long long* __restrict__ records,
    int E, float inv_num, int B)
{
    __shared__ int hist[MAXB];                 // counts, then global-base cursors
    const int  op   = blockIdx.y;
    const long base = (long)op * (long)E;
    const int  e0   = blockIdx.x * CHUNK;
    const int  e1   = min(e0 + CHUNK, E);
    const float wscale = ws[op] * inv_num;

    for (int i = threadIdx.x; i < B; i += 256) hist[i] = 0;
    __syncthreads();
    for (int e = e0 + threadIdx.x; e < e1; e += 256)
        atomicAdd(&hist[edge_rows[base + e] >> RPB_SHIFT], 1);
    __syncthreads();
    for (int i = threadIdx.x; i < B; i += 256) {
        const int c = hist[i];
        hist[i] = c ? atomicAdd(&gcursor[i], c) : 0;   // reserve run, one atomic/bin
    }
    __syncthreads();
    for (int e = e0 + threadIdx.x; e < e1; e += 256) {
        const int   row = edge_rows[base + e];         // L2 re-hit from pass 1
        const int   col = __builtin_nontemporal_load(&edge_cols[base + e]);
        const float v   = __builtin_nontemporal_load(&edge_vals[base + e]) * wscale;
        const int   pos = atomicAdd(&hist[row >> RPB_SHIFT], 1);
        const unsigned long long rec =
            ((unsigned long long)__float_as_uint(v) << 32)
            | ((unsigned int)(row & (RPB - 1)) << 16) | (unsigned int)col;
        records[pos] = rec;                            // plain store -> L2 merge
    }
}

// ---------- 4. filter gather: ONE block per bucket, 16 waves x 2 rows ----------
__global__ __launch_bounds__(1024) void gather_filter2_kernel(
    const unsigned short* __restrict__ xh, const int* __restrict__ boff,
    const unsigned long long* __restrict__ records, float* __restrict__ out, int N)
{
    const int lane = threadIdx.x & 63;
    const int wv   = threadIdx.x >> 6;              // 0..15
    const int bkt  = blockIdx.x;
    const int row0 = (bkt << RPB_SHIFT) + wv * 2;   // this wave's two rows
    const int row1 = row0 + 1;

    const int start = boff[bkt], end = boff[bkt + 1];

    float a0x = 0.f, a0y = 0.f, a1x = 0.f, a1y = 0.f;
    for (int c = start; c < end; c += 64) {
        const int idx = c + lane;
        unsigned int lo = 0xFFFF0000u, hi = 0;      // invalid: rl field = 0xFFFF
        if (idx < end) {
            const unsigned long long r =
                __builtin_nontemporal_load(&records[idx]);
            lo = (unsigned int)r;
            hi = (unsigned int)(r >> 32);
        }
        unsigned long long mask = __ballot((lo >> 17) == (unsigned int)wv);
        while (mask) {
            const int j = __ffsll(mask) - 1;
            mask &= mask - 1;
            const unsigned int lj = __shfl(lo, j);   // wave-uniform
            const float v = __uint_as_float(__shfl(hi, j));
            const unsigned int col = lj & 0xFFFFu;
            const unsigned int p = *reinterpret_cast<const unsigned int*>(
                xh + (size_t)col * D_DIM + lane * 2);
            const float px = __uint_as_float(p << 16);
            const float py = __uint_as_float(p & 0xFFFF0000u);
            if (lj & 0x10000u) { a1x += v * px; a1y += v * py; }   // rl odd
            else               { a0x += v * px; a0y += v * py; }   // rl even
        }
    }
    if (row0 < N)
        __builtin_nontemporal_store(pack2f(a0x, a0y),
            reinterpret_cast<unsigned long long*>(out + (size_t)row0 * D_DIM + lane * 2));
    if (row1 < N)
        __builtin_nontemporal_store(pack2f(a1x, a1y),
            reinterpret_cast<unsigned long long*>(out + (size_t)row1 * D_DIM + lane * 2));
}

extern "C" void kernel_launch(void* const* d_in, const int* in_sizes, int n_in,
                              void* d_out, int out_size, void* d_ws, size_t ws_size,
                              hipStream_t stream)
{
    const float* x         = (const float*)d_in[0];
    const float* edge_vals = (const float*)d_in[1];
    const float* ws        = (const float*)d_in[2];
    const int*   edge_rows = (const int*)d_in[3];
    const int*   edge_cols = (const int*)d_in[4];
    float*       out       = (float*)d_out;

    const int num_op = in_sizes[2];               // 8
    const int E      = in_sizes[1] / num_op;      // 400000
    const int N      = in_sizes[0] / D_DIM;       // 50000
    const long Etot  = (long)num_op * (long)E;    // 3.2M
    const int  B     = (N + RPB - 1) / RPB;       // 1563 buckets
    const float inv_num = 1.0f / (float)num_op;

    // workspace layout: boff | gcursor | x_bf16 | records
    const size_t off_boff    = 0;
    const size_t off_gcur    = ((size_t)(B + 1) * 4 + 255) & ~(size_t)255;
    const size_t off_xh      = (off_gcur + (size_t)B * 4 + 255) & ~(size_t)255;
    const size_t off_records = (off_xh + (size_t)N * D_DIM * 2 + 255) & ~(size_t)255;
    const size_t need        = off_records + (size_t)Etot * 8;

    if (ws_size < need || B > MAXB || N > 65535) {
        (void)hipMemsetAsync(d_out, 0, (size_t)out_size * sizeof(float), stream);
        dim3 grid(256, num_op, 1);
        spmm_scatter_kernel<<<grid, 256, 0, stream>>>(
            x, edge_vals, ws, edge_rows, edge_cols, out, E, inv_num);
        return;
    }

    int* boff    = (int*)((char*)d_ws + off_boff);
    int* gcursor = (int*)((char*)d_ws + off_gcur);
    unsigned short* xh = (unsigned short*)((char*)d_ws + off_xh);
    unsigned long long* records = (unsigned long long*)((char*)d_ws + off_records);

    (void)hipMemsetAsync(gcursor, 0, (size_t)B * 4, stream);

    convert_kernel<<<1024, 256, 0, stream>>>(
        (const float4*)x, (unsigned long long*)xh, N * D_DIM / 4);

    bucket_count_kernel<<<256, 256, 0, stream>>>(edge_rows, gcursor, Etot, B);
    scan_kernel<<<1, SCAN_BLOCK, 0, stream>>>(gcursor, boff, B);

    dim3 sgrid((E + CHUNK - 1) / CHUNK, num_op, 1);   // 25 x 8 blocks
    scatter_bucket_kernel<<<sgrid, 256, 0, stream>>>(
        edge_rows, edge_cols, edge_vals, ws, gcursor, records, E, inv_num, B);

    // one block per bucket: 16 waves, 2 rows/wave
    gather_filter2_kernel<<<B, 1024, 0, stream>>>(xh, boff, records, out, N);
}

// Round 8
// 251.699 us; speedup vs baseline: 1.7433x; 1.7433x over previous
//
#include <hip/hip_runtime.h>

// Op: out = (1/num_op) * sum_i ws[i] * SpMM(A_i, x).
// Pipeline: x->bf16 | bucket count (row>>5) | scan | bucketed scatter |
//           per-bucket exact-row sort (LDS rank, L2-local) |
//           wave-per-row gather with scalarized record stream.
// N=50000, D=128, NUM_OP=8, E=400000.

#define D_DIM 128
#define RPB_SHIFT 5
#define RPB 32
#define MAXB 2048
#define CHUNK 16384
#define SCAN_BLOCK 1024

typedef unsigned long long ull;

static __device__ __forceinline__ unsigned short f2bf(float f) {
    unsigned int u = __float_as_uint(f);
    u += 0x7FFFu + ((u >> 16) & 1u);          // round-to-nearest-even
    return (unsigned short)(u >> 16);
}

static __device__ __forceinline__ ull pack2f(float a, float b) {
    return (ull)__float_as_uint(a) | ((ull)__float_as_uint(b) << 32);
}

// ---------- fallback (round-0) atomic scatter kernel ----------
__global__ __launch_bounds__(256) void spmm_scatter_kernel(
    const float* __restrict__ x, const float* __restrict__ edge_vals,
    const float* __restrict__ ws, const int* __restrict__ edge_rows,
    const int* __restrict__ edge_cols, float* __restrict__ out,
    int E, float inv_num)
{
    const int  op   = blockIdx.y;
    const long base = (long)op * (long)E;
    const float wscale = ws[op] * inv_num;
    const int lane = threadIdx.x & 63;
    const int wave = blockIdx.x * (blockDim.x >> 6) + (threadIdx.x >> 6);
    const int nwaves = gridDim.x * (blockDim.x >> 6);
    for (int e = wave; e < E; e += nwaves) {
        const int row = edge_rows[base + e];
        const int col = edge_cols[base + e];
        const float v = edge_vals[base + e] * wscale;
        const float2 xv = *reinterpret_cast<const float2*>(x + (long)col * D_DIM + lane * 2);
        float* o = out + (long)row * D_DIM + lane * 2;
        atomicAdd(o, xv.x * v);
        atomicAdd(o + 1, xv.y * v);
    }
}

// ---------- 0. x (f32) -> bf16 ----------
__global__ __launch_bounds__(256) void convert_kernel(
    const float4* __restrict__ x4, ull* __restrict__ xh, int n4)
{
    const int stride = gridDim.x * blockDim.x;
    for (int i = blockIdx.x * blockDim.x + threadIdx.x; i < n4; i += stride) {
        const float4 v = x4[i];
        const ull p =
            (ull)f2bf(v.x)
            | ((ull)f2bf(v.y) << 16)
            | ((ull)f2bf(v.z) << 32)
            | ((ull)f2bf(v.w) << 48);
        xh[i] = p;
    }
}

// ---------- 1. coarse bucket count (LDS-aggregated) ----------
__global__ __launch_bounds__(256) void bucket_count_kernel(
    const int* __restrict__ rows, int* __restrict__ gcount, long n, int B)
{
    __shared__ int h[MAXB];
    for (int i = threadIdx.x; i < B; i += 256) h[i] = 0;
    __syncthreads();
    for (long e = (long)blockIdx.x * 256 + threadIdx.x; e < n;
         e += (long)gridDim.x * 256)
        atomicAdd(&h[__builtin_nontemporal_load(&rows[e]) >> RPB_SHIFT], 1);
    __syncthreads();
    for (int i = threadIdx.x; i < B; i += 256)
        if (h[i]) atomicAdd(&gcount[i], h[i]);
}

// ---------- 2. exclusive scan (single block, proven multi-tile) ----------
__global__ __launch_bounds__(SCAN_BLOCK) void scan_kernel(
    int* __restrict__ cursors, int* __restrict__ offsets, int N)
{
    __shared__ int sdata[SCAN_BLOCK];
    __shared__ int carry_s;
    if (threadIdx.x == 0) carry_s = 0;
    __syncthreads();
    for (int base = 0; base < N; base += SCAN_BLOCK) {
        const int i = base + (int)threadIdx.x;
        const int v = (i < N) ? cursors[i] : 0;
        sdata[threadIdx.x] = v;
        __syncthreads();
        for (int ofs = 1; ofs < SCAN_BLOCK; ofs <<= 1) {
            int t = (threadIdx.x >= (unsigned)ofs) ? sdata[threadIdx.x - ofs] : 0;
            __syncthreads();
            sdata[threadIdx.x] += t;
            __syncthreads();
        }
        const int incl  = sdata[threadIdx.x];
        const int carry = carry_s;
        if (i < N) {
            const int excl = carry + incl - v;
            offsets[i] = excl;
            cursors[i] = excl;
        }
        __syncthreads();
        if (threadIdx.x == SCAN_BLOCK - 1) carry_s = carry + incl;
        __syncthreads();
    }
    if (threadIdx.x == 0) offsets[N] = carry_s;
}

// ---------- 3. bucketed scatter: per-block reservation + LDS rank ----------
__global__ __launch_bounds__(256) void scatter_bucket_kernel(
    const int* __restrict__ edge_rows, const int* __restrict__ edge_cols,
    const float* __restrict__ edge_vals, const float* __restrict__ ws,
    int* __restrict__ gcursor, ull* __restrict__ records,
    int E, float inv_num, int B)
{
    __shared__ int hist[MAXB];                 // counts, then global-base cursors
    const int  op   = blockIdx.y;
    const long base = (long)op * (long)E;
    const int  e0   = blockIdx.x * CHUNK;
    const int  e1   = min(e0 + CHUNK, E);
    const float wscale = ws[op] * inv_num;

    for (int i = threadIdx.x; i < B; i += 256) hist[i] = 0;
    __syncthreads();
    for (int e = e0 + threadIdx.x; e < e1; e += 256)
        atomicAdd(&hist[edge_rows[base + e] >> RPB_SHIFT], 1);
    __syncthreads();
    for (int i = threadIdx.x; i < B; i += 256) {
        const int c = hist[i];
        hist[i] = c ? atomicAdd(&gcursor[i], c) : 0;   // reserve run, one atomic/bin
    }
    __syncthreads();
    for (int e = e0 + threadIdx.x; e < e1; e += 256) {
        const int   row = edge_rows[base + e];         // L2 re-hit from pass 1
        const int   col = __builtin_nontemporal_load(&edge_cols[base + e]);
        const float v   = __builtin_nontemporal_load(&edge_vals[base + e]) * wscale;
        const int   pos = atomicAdd(&hist[row >> RPB_SHIFT], 1);
        const ull rec =
            ((ull)__float_as_uint(v) << 32)
            | ((unsigned int)(row & (RPB - 1)) << 16) | (unsigned int)col;
        records[pos] = rec;                            // plain store -> L2 merge
    }
}

// ---------- 3b. per-bucket exact-row sort (L2-local) ----------
__global__ __launch_bounds__(256) void sort_bucket_kernel(
    const ull* __restrict__ records, ull* __restrict__ sorted,
    const int* __restrict__ boff, int* __restrict__ rowoff, int N, int B)
{
    __shared__ int h[RPB];
    __shared__ int cur[RPB];
    const int bkt   = blockIdx.x;
    const int start = boff[bkt], end = boff[bkt + 1];
    const int row0  = bkt << RPB_SHIFT;

    if (threadIdx.x < RPB) h[threadIdx.x] = 0;
    __syncthreads();
    for (int i = start + (int)threadIdx.x; i < end; i += 256) {
        const unsigned int lo = (unsigned int)records[i];
        atomicAdd(&h[lo >> 16], 1);
    }
    __syncthreads();
    if (threadIdx.x == 0) {
        int run = start;
        for (int r = 0; r < RPB; ++r) {
            cur[r] = run;
            const int row = row0 + r;
            if (row <= N) rowoff[row] = run;
            run += h[r];
        }
        if (bkt == B - 1 && row0 + RPB <= N) rowoff[N] = run;  // sentinel when N%RPB==0
    }
    __syncthreads();
    for (int i = start + (int)threadIdx.x; i < end; i += 256) {
        const ull r = records[i];
        const int rl = (int)(((unsigned int)r) >> 16) & (RPB - 1);
        const int pos = atomicAdd(&cur[rl], 1);
        sorted[pos] = r;                     // stays within 16KB L2-resident region
    }
}

// ---------- 4. gather: wave per row, scalarized record stream ----------
#define GPROC(R)                                                               \
    {                                                                          \
        const unsigned int col_ = (unsigned int)(R)&0xFFFFu;                   \
        const float v_ = __uint_as_float((unsigned int)((R) >> 32));           \
        const unsigned int p_ = *reinterpret_cast<const unsigned int*>(        \
            xh + (size_t)col_ * D_DIM + lane * 2);                             \
        ax += v_ * __uint_as_float(p_ << 16);                                  \
        ay += v_ * __uint_as_float(p_ & 0xFFFF0000u);                          \
    }

__global__ __launch_bounds__(256) void gather_sorted_kernel(
    const unsigned short* __restrict__ xh, const int* __restrict__ rowoff,
    const ull* __restrict__ sorted, float* __restrict__ out, int N)
{
    const int lane = threadIdx.x & 63;
    const int row  = blockIdx.x * 4 + (threadIdx.x >> 6);
    if (row >= N) return;

    // force wave-uniform bounds into SGPRs -> record loop scalarizes (s_load)
    const int start = __builtin_amdgcn_readfirstlane(rowoff[row]);
    const int end   = __builtin_amdgcn_readfirstlane(rowoff[row + 1]);

    float ax = 0.f, ay = 0.f;
    int j = start;
    for (; j + 3 < end; j += 4) {            // 4 independent x-loads in flight
        const ull r0 = sorted[j];
        const ull r1 = sorted[j + 1];
        const ull r2 = sorted[j + 2];
        const ull r3 = sorted[j + 3];
        GPROC(r0) GPROC(r1) GPROC(r2) GPROC(r3)
    }
    for (; j < end; ++j) {
        const ull r0 = sorted[j];
        GPROC(r0)
    }
    __builtin_nontemporal_store(pack2f(ax, ay),
        reinterpret_cast<ull*>(out + (size_t)row * D_DIM + lane * 2));
}

// ---------- 4-alt (round-7 proven): ballot-filter gather ----------
__global__ __launch_bounds__(1024) void gather_filter2_kernel(
    const unsigned short* __restrict__ xh, const int* __restrict__ boff,
    const ull* __restrict__ records, float* __restrict__ out, int N)
{
    const int lane = threadIdx.x & 63;
    const int wv   = threadIdx.x >> 6;
    const int bkt  = blockIdx.x;
    const int row0 = (bkt << RPB_SHIFT) + wv * 2;
    const int row1 = row0 + 1;
    const int start = boff[bkt], end = boff[bkt + 1];

    float a0x = 0.f, a0y = 0.f, a1x = 0.f, a1y = 0.f;
    for (int c = start; c < end; c += 64) {
        const int idx = c + lane;
        unsigned int lo = 0xFFFF0000u, hi = 0;
        if (idx < end) {
            const ull r = __builtin_nontemporal_load(&records[idx]);
            lo = (unsigned int)r;
            hi = (unsigned int)(r >> 32);
        }
        ull mask = __ballot((lo >> 17) == (unsigned int)wv);
        while (mask) {
            const int j = __ffsll(mask) - 1;
            mask &= mask - 1;
            const unsigned int lj = __shfl(lo, j);
            const float v = __uint_as_float(__shfl(hi, j));
            const unsigned int col = lj & 0xFFFFu;
            const unsigned int p = *reinterpret_cast<const unsigned int*>(
                xh + (size_t)col * D_DIM + lane * 2);
            const float px = __uint_as_float(p << 16);
            const float py = __uint_as_float(p & 0xFFFF0000u);
            if (lj & 0x10000u) { a1x += v * px; a1y += v * py; }
            else               { a0x += v * px; a0y += v * py; }
        }
    }
    if (row0 < N)
        __builtin_nontemporal_store(pack2f(a0x, a0y),
            reinterpret_cast<ull*>(out + (size_t)row0 * D_DIM + lane * 2));
    if (row1 < N)
        __builtin_nontemporal_store(pack2f(a1x, a1y),
            reinterpret_cast<ull*>(out + (size_t)row1 * D_DIM + lane * 2));
}

extern "C" void kernel_launch(void* const* d_in, const int* in_sizes, int n_in,
                              void* d_out, int out_size, void* d_ws, size_t ws_size,
                              hipStream_t stream)
{
    const float* x         = (const float*)d_in[0];
    const float* edge_vals = (const float*)d_in[1];
    const float* ws        = (const float*)d_in[2];
    const int*   edge_rows = (const int*)d_in[3];
    const int*   edge_cols = (const int*)d_in[4];
    float*       out       = (float*)d_out;

    const int num_op = in_sizes[2];               // 8
    const int E      = in_sizes[1] / num_op;      // 400000
    const int N      = in_sizes[0] / D_DIM;       // 50000
    const long Etot  = (long)num_op * (long)E;    // 3.2M
    const int  B     = (N + RPB - 1) / RPB;       // 1563 buckets
    const float inv_num = 1.0f / (float)num_op;

    // workspace layout: boff | gcursor | rowoff | xh | records | sorted
    const size_t off_boff    = 0;
    const size_t off_gcur    = ((size_t)(B + 1) * 4 + 255) & ~(size_t)255;
    const size_t off_rowoff  = (off_gcur + (size_t)B * 4 + 255) & ~(size_t)255;
    const size_t off_xh      = (off_rowoff + (size_t)(N + 1) * 4 + 255) & ~(size_t)255;
    const size_t off_records = (off_xh + (size_t)N * D_DIM * 2 + 255) & ~(size_t)255;
    const size_t off_sorted  = off_records + (size_t)Etot * 8;
    const size_t need_sort   = off_sorted + (size_t)Etot * 8;
    const size_t need_filter = off_sorted;        // without the sorted buffer

    if (ws_size < need_filter || B > MAXB || N > 65535) {
        (void)hipMemsetAsync(d_out, 0, (size_t)out_size * sizeof(float), stream);
        dim3 grid(256, num_op, 1);
        spmm_scatter_kernel<<<grid, 256, 0, stream>>>(
            x, edge_vals, ws, edge_rows, edge_cols, out, E, inv_num);
        return;
    }

    int* boff    = (int*)((char*)d_ws + off_boff);
    int* gcursor = (int*)((char*)d_ws + off_gcur);
    int* rowoff  = (int*)((char*)d_ws + off_rowoff);
    unsigned short* xh = (unsigned short*)((char*)d_ws + off_xh);
    ull* records = (ull*)((char*)d_ws + off_records);
    ull* sorted  = (ull*)((char*)d_ws + off_sorted);

    (void)hipMemsetAsync(gcursor, 0, (size_t)B * 4, stream);

    convert_kernel<<<1024, 256, 0, stream>>>(
        (const float4*)x, (ull*)xh, N * D_DIM / 4);

    bucket_count_kernel<<<256, 256, 0, stream>>>(edge_rows, gcursor, Etot, B);
    scan_kernel<<<1, SCAN_BLOCK, 0, stream>>>(gcursor, boff, B);

    dim3 sgrid((E + CHUNK - 1) / CHUNK, num_op, 1);
    scatter_bucket_kernel<<<sgrid, 256, 0, stream>>>(
        edge_rows, edge_cols, edge_vals, ws, gcursor, records, E, inv_num, B);

    if (ws_size >= need_sort) {
        sort_bucket_kernel<<<B, 256, 0, stream>>>(records, sorted, boff, rowoff, N, B);
        gather_sorted_kernel<<<(N + 3) / 4, 256, 0, stream>>>(xh, rowoff, sorted, out, N);
    } else {
        gather_filter2_kernel<<<B, 1024, 0, stream>>>(xh, boff, records, out, N);
    }
}

// Round 9
// 223.314 us; speedup vs baseline: 1.9649x; 1.1271x over previous
//
#include <hip/hip_runtime.h>

// Op: out = (1/num_op) * sum_i ws[i] * SpMM(A_i, x).
// Pipeline: x->bf16 | bucket count (row>>5) | scan | bucketed scatter |
//           per-bucket exact-row sort (LDS rank, L2-local) |
//           wave-per-row gather with scalarized record stream.
// N=50000, D=128, NUM_OP=8, E=400000.

#define D_DIM 128
#define RPB_SHIFT 5
#define RPB 32
#define MAXB 2048
#define CHUNK 8192
#define SCAN_BLOCK 1024

typedef unsigned long long ull;

static __device__ __forceinline__ unsigned short f2bf(float f) {
    unsigned int u = __float_as_uint(f);
    u += 0x7FFFu + ((u >> 16) & 1u);          // round-to-nearest-even
    return (unsigned short)(u >> 16);
}

static __device__ __forceinline__ ull pack2f(float a, float b) {
    return (ull)__float_as_uint(a) | ((ull)__float_as_uint(b) << 32);
}

// ---------- fallback (round-0) atomic scatter kernel ----------
__global__ __launch_bounds__(256) void spmm_scatter_kernel(
    const float* __restrict__ x, const float* __restrict__ edge_vals,
    const float* __restrict__ ws, const int* __restrict__ edge_rows,
    const int* __restrict__ edge_cols, float* __restrict__ out,
    int E, float inv_num)
{
    const int  op   = blockIdx.y;
    const long base = (long)op * (long)E;
    const float wscale = ws[op] * inv_num;
    const int lane = threadIdx.x & 63;
    const int wave = blockIdx.x * (blockDim.x >> 6) + (threadIdx.x >> 6);
    const int nwaves = gridDim.x * (blockDim.x >> 6);
    for (int e = wave; e < E; e += nwaves) {
        const int row = edge_rows[base + e];
        const int col = edge_cols[base + e];
        const float v = edge_vals[base + e] * wscale;
        const float2 xv = *reinterpret_cast<const float2*>(x + (long)col * D_DIM + lane * 2);
        float* o = out + (long)row * D_DIM + lane * 2;
        atomicAdd(o, xv.x * v);
        atomicAdd(o + 1, xv.y * v);
    }
}

// ---------- 0. x (f32) -> bf16 ----------
__global__ __launch_bounds__(256) void convert_kernel(
    const float4* __restrict__ x4, ull* __restrict__ xh, int n4)
{
    const int stride = gridDim.x * blockDim.x;
    for (int i = blockIdx.x * blockDim.x + threadIdx.x; i < n4; i += stride) {
        const float4 v = x4[i];
        const ull p =
            (ull)f2bf(v.x)
            | ((ull)f2bf(v.y) << 16)
            | ((ull)f2bf(v.z) << 32)
            | ((ull)f2bf(v.w) << 48);
        xh[i] = p;
    }
}

// ---------- 1. coarse bucket count (LDS-aggregated, 16 waves/block) ----------
__global__ __launch_bounds__(1024) void bucket_count_kernel(
    const int* __restrict__ rows, int* __restrict__ gcount, long n, int B)
{
    __shared__ int h[MAXB];
    for (int i = threadIdx.x; i < B; i += 1024) h[i] = 0;
    __syncthreads();
    for (long e = (long)blockIdx.x * 1024 + threadIdx.x; e < n;
         e += (long)gridDim.x * 1024)
        atomicAdd(&h[__builtin_nontemporal_load(&rows[e]) >> RPB_SHIFT], 1);
    __syncthreads();
    for (int i = threadIdx.x; i < B; i += 1024)
        if (h[i]) atomicAdd(&gcount[i], h[i]);
}

// ---------- 2. exclusive scan (single block, proven multi-tile) ----------
__global__ __launch_bounds__(SCAN_BLOCK) void scan_kernel(
    int* __restrict__ cursors, int* __restrict__ offsets, int N)
{
    __shared__ int sdata[SCAN_BLOCK];
    __shared__ int carry_s;
    if (threadIdx.x == 0) carry_s = 0;
    __syncthreads();
    for (int base = 0; base < N; base += SCAN_BLOCK) {
        const int i = base + (int)threadIdx.x;
        const int v = (i < N) ? cursors[i] : 0;
        sdata[threadIdx.x] = v;
        __syncthreads();
        for (int ofs = 1; ofs < SCAN_BLOCK; ofs <<= 1) {
            int t = (threadIdx.x >= (unsigned)ofs) ? sdata[threadIdx.x - ofs] : 0;
            __syncthreads();
            sdata[threadIdx.x] += t;
            __syncthreads();
        }
        const int incl  = sdata[threadIdx.x];
        const int carry = carry_s;
        if (i < N) {
            const int excl = carry + incl - v;
            offsets[i] = excl;
            cursors[i] = excl;
        }
        __syncthreads();
        if (threadIdx.x == SCAN_BLOCK - 1) carry_s = carry + incl;
        __syncthreads();
    }
    if (threadIdx.x == 0) offsets[N] = carry_s;
}

// ---------- 3. bucketed scatter: per-block reservation + LDS rank ----------
__global__ __launch_bounds__(1024) void scatter_bucket_kernel(
    const int* __restrict__ edge_rows, const int* __restrict__ edge_cols,
    const float* __restrict__ edge_vals, const float* __restrict__ ws,
    int* __restrict__ gcursor, ull* __restrict__ records,
    int E, float inv_num, int B)
{
    __shared__ int hist[MAXB];                 // counts, then global-base cursors
    const int  op   = blockIdx.y;
    const long base = (long)op * (long)E;
    const int  e0   = blockIdx.x * CHUNK;
    const int  e1   = min(e0 + CHUNK, E);
    const float wscale = ws[op] * inv_num;

    for (int i = threadIdx.x; i < B; i += 1024) hist[i] = 0;
    __syncthreads();
    for (int e = e0 + threadIdx.x; e < e1; e += 1024)
        atomicAdd(&hist[edge_rows[base + e] >> RPB_SHIFT], 1);
    __syncthreads();
    for (int i = threadIdx.x; i < B; i += 1024) {
        const int c = hist[i];
        hist[i] = c ? atomicAdd(&gcursor[i], c) : 0;   // reserve run, one atomic/bin
    }
    __syncthreads();
    for (int e = e0 + threadIdx.x; e < e1; e += 1024) {
        const int   row = edge_rows[base + e];         // L2 re-hit from pass 1
        const int   col = __builtin_nontemporal_load(&edge_cols[base + e]);
        const float v   = __builtin_nontemporal_load(&edge_vals[base + e]) * wscale;
        const int   pos = atomicAdd(&hist[row >> RPB_SHIFT], 1);
        const ull rec =
            ((ull)__float_as_uint(v) << 32)
            | ((unsigned int)(row & (RPB - 1)) << 16) | (unsigned int)col;
        records[pos] = rec;                            // plain store -> L2 merge
    }
}

// ---------- 3b. per-bucket exact-row sort (L2-local) ----------
__global__ __launch_bounds__(256) void sort_bucket_kernel(
    const ull* __restrict__ records, ull* __restrict__ sorted,
    const int* __restrict__ boff, int* __restrict__ rowoff, int N, int B)
{
    __shared__ int h[RPB];
    __shared__ int cur[RPB];
    const int bkt   = blockIdx.x;
    const int start = boff[bkt], end = boff[bkt + 1];
    const int row0  = bkt << RPB_SHIFT;

    if (threadIdx.x < RPB) h[threadIdx.x] = 0;
    __syncthreads();
    for (int i = start + (int)threadIdx.x; i < end; i += 256) {
        const unsigned int lo = (unsigned int)records[i];
        atomicAdd(&h[lo >> 16], 1);
    }
    __syncthreads();
    if (threadIdx.x == 0) {
        int run = start;
        for (int r = 0; r < RPB; ++r) {
            cur[r] = run;
            const int row = row0 + r;
            if (row <= N) rowoff[row] = run;
            run += h[r];
        }
        if (bkt == B - 1 && row0 + RPB <= N) rowoff[N] = run;  // sentinel when N%RPB==0
    }
    __syncthreads();
    for (int i = start + (int)threadIdx.x; i < end; i += 256) {
        const ull r = records[i];
        const int rl = (int)(((unsigned int)r) >> 16) & (RPB - 1);
        const int pos = atomicAdd(&cur[rl], 1);
        sorted[pos] = r;                     // stays within 16KB L2-resident region
    }
}

// ---------- 4. gather: wave per row, scalarized record stream ----------
#define GPROC(R)                                                               \
    {                                                                          \
        const unsigned int col_ = (unsigned int)(R)&0xFFFFu;                   \
        const float v_ = __uint_as_float((unsigned int)((R) >> 32));           \
        const unsigned int p_ = *reinterpret_cast<const unsigned int*>(        \
            xh + (size_t)col_ * D_DIM + lane * 2);                             \
        ax += v_ * __uint_as_float(p_ << 16);                                  \
        ay += v_ * __uint_as_float(p_ & 0xFFFF0000u);                          \
    }

__global__ __launch_bounds__(256) void gather_sorted_kernel(
    const unsigned short* __restrict__ xh, const int* __restrict__ rowoff,
    const ull* __restrict__ sorted, float* __restrict__ out, int N)
{
    const int lane = threadIdx.x & 63;
    const int row  = blockIdx.x * 4 + (threadIdx.x >> 6);
    if (row >= N) return;

    // force wave-uniform bounds into SGPRs -> record loop scalarizes (s_load)
    const int start = __builtin_amdgcn_readfirstlane(rowoff[row]);
    const int end   = __builtin_amdgcn_readfirstlane(rowoff[row + 1]);

    float ax = 0.f, ay = 0.f;
    int j = start;
    for (; j + 3 < end; j += 4) {            // 4 independent x-loads in flight
        const ull r0 = sorted[j];
        const ull r1 = sorted[j + 1];
        const ull r2 = sorted[j + 2];
        const ull r3 = sorted[j + 3];
        GPROC(r0) GPROC(r1) GPROC(r2) GPROC(r3)
    }
    for (; j < end; ++j) {
        const ull r0 = sorted[j];
        GPROC(r0)
    }
    __builtin_nontemporal_store(pack2f(ax, ay),
        reinterpret_cast<ull*>(out + (size_t)row * D_DIM + lane * 2));
}

// ---------- 4-alt (round-7 proven): ballot-filter gather ----------
__global__ __launch_bounds__(1024) void gather_filter2_kernel(
    const unsigned short* __restrict__ xh, const int* __restrict__ boff,
    const ull* __restrict__ records, float* __restrict__ out, int N)
{
    const int lane = threadIdx.x & 63;
    const int wv   = threadIdx.x >> 6;
    const int bkt  = blockIdx.x;
    const int row0 = (bkt << RPB_SHIFT) + wv * 2;
    const int row1 = row0 + 1;
    const int start = boff[bkt], end = boff[bkt + 1];

    float a0x = 0.f, a0y = 0.f, a1x = 0.f, a1y = 0.f;
    for (int c = start; c < end; c += 64) {
        const int idx = c + lane;
        unsigned int lo = 0xFFFF0000u, hi = 0;
        if (idx < end) {
            const ull r = __builtin_nontemporal_load(&records[idx]);
            lo = (unsigned int)r;
            hi = (unsigned int)(r >> 32);
        }
        ull mask = __ballot((lo >> 17) == (unsigned int)wv);
        while (mask) {
            const int j = __ffsll(mask) - 1;
            mask &= mask - 1;
            const unsigned int lj = __shfl(lo, j);
            const float v = __uint_as_float(__shfl(hi, j));
            const unsigned int col = lj & 0xFFFFu;
            const unsigned int p = *reinterpret_cast<const unsigned int*>(
                xh + (size_t)col * D_DIM + lane * 2);
            const float px = __uint_as_float(p << 16);
            const float py = __uint_as_float(p & 0xFFFF0000u);
            if (lj & 0x10000u) { a1x += v * px; a1y += v * py; }
            else               { a0x += v * px; a0y += v * py; }
        }
    }
    if (row0 < N)
        __builtin_nontemporal_store(pack2f(a0x, a0y),
            reinterpret_cast<ull*>(out + (size_t)row0 * D_DIM + lane * 2));
    if (row1 < N)
        __builtin_nontemporal_store(pack2f(a1x, a1y),
            reinterpret_cast<ull*>(out + (size_t)row1 * D_DIM + lane * 2));
}

extern "C" void kernel_launch(void* const* d_in, const int* in_sizes, int n_in,
                              void* d_out, int out_size, void* d_ws, size_t ws_size,
                              hipStream_t stream)
{
    const float* x         = (const float*)d_in[0];
    const float* edge_vals = (const float*)d_in[1];
    const float* ws        = (const float*)d_in[2];
    const int*   edge_rows = (const int*)d_in[3];
    const int*   edge_cols = (const int*)d_in[4];
    float*       out       = (float*)d_out;

    const int num_op = in_sizes[2];               // 8
    const int E      = in_sizes[1] / num_op;      // 400000
    const int N      = in_sizes[0] / D_DIM;       // 50000
    const long Etot  = (long)num_op * (long)E;    // 3.2M
    const int  B     = (N + RPB - 1) / RPB;       // 1563 buckets
    const float inv_num = 1.0f / (float)num_op;

    // workspace layout: boff | gcursor | rowoff | xh | records | sorted
    const size_t off_boff    = 0;
    const size_t off_gcur    = ((size_t)(B + 1) * 4 + 255) & ~(size_t)255;
    const size_t off_rowoff  = (off_gcur + (size_t)B * 4 + 255) & ~(size_t)255;
    const size_t off_xh      = (off_rowoff + (size_t)(N + 1) * 4 + 255) & ~(size_t)255;
    const size_t off_records = (off_xh + (size_t)N * D_DIM * 2 + 255) & ~(size_t)255;
    const size_t off_sorted  = off_records + (size_t)Etot * 8;
    const size_t need_sort   = off_sorted + (size_t)Etot * 8;
    const size_t need_filter = off_sorted;        // without the sorted buffer

    if (ws_size < need_filter || B > MAXB || N > 65535) {
        (void)hipMemsetAsync(d_out, 0, (size_t)out_size * sizeof(float), stream);
        dim3 grid(256, num_op, 1);
        spmm_scatter_kernel<<<grid, 256, 0, stream>>>(
            x, edge_vals, ws, edge_rows, edge_cols, out, E, inv_num);
        return;
    }

    int* boff    = (int*)((char*)d_ws + off_boff);
    int* gcursor = (int*)((char*)d_ws + off_gcur);
    int* rowoff  = (int*)((char*)d_ws + off_rowoff);
    unsigned short* xh = (unsigned short*)((char*)d_ws + off_xh);
    ull* records = (ull*)((char*)d_ws + off_records);
    ull* sorted  = (ull*)((char*)d_ws + off_sorted);

    (void)hipMemsetAsync(gcursor, 0, (size_t)B * 4, stream);

    convert_kernel<<<1024, 256, 0, stream>>>(
        (const float4*)x, (ull*)xh, N * D_DIM / 4);

    bucket_count_kernel<<<256, 1024, 0, stream>>>(edge_rows, gcursor, Etot, B);
    scan_kernel<<<1, SCAN_BLOCK, 0, stream>>>(gcursor, boff, B);

    dim3 sgrid((E + CHUNK - 1) / CHUNK, num_op, 1);   // 49 x 8 = 392 blocks, 16 waves
    scatter_bucket_kernel<<<sgrid, 1024, 0, stream>>>(
        edge_rows, edge_cols, edge_vals, ws, gcursor, records, E, inv_num, B);

    if (ws_size >= need_sort) {
        sort_bucket_kernel<<<B, 256, 0, stream>>>(records, sorted, boff, rowoff, N, B);
        gather_sorted_kernel<<<(N + 3) / 4, 256, 0, stream>>>(xh, rowoff, sorted, out, N);
    } else {
        gather_filter2_kernel<<<B, 1024, 0, stream>>>(xh, boff, records, out, N);
    }
}